// Round 4
// baseline (314.917 us; speedup 1.0000x reference)
//
#include <hip/hip_runtime.h>
#include <hip/hip_fp16.h>
#include <math.h>
#include <stdint.h>

// VQ via f16x3 split MFMA: dot = (hi.hi + hi.lo + lo.hi) * 2^-20, planes = f16(1024*x).
// diff = (v2 - 2*dot) + c2 fp32-rounded per np; argmin codes 1..4095, ties -> lowest n.
// V hi/lo planes are pre-split into d_out (gather overwrites it at the end).

#define M_TOTAL 16384
#define NCODES  4096
#define D_DIM   256

#define OUT_OFF_IDX  (M_TOTAL * D_DIM)
#define OUT_OFF_LOSS (OUT_OFF_IDX + M_TOTAL)

#define NPART 16          // n-dim grid splits (4096 / 256)
#define WPLANE (NCODES * D_DIM)
#define VPLANE (M_TOTAL * D_DIM)

typedef _Float16 half8 __attribute__((ext_vector_type(8)));
typedef _Float16 half4v __attribute__((ext_vector_type(4)));
typedef float    float4v __attribute__((ext_vector_type(4)));

__device__ __forceinline__ void dma16(const _Float16* g, _Float16* l) {
  __builtin_amdgcn_global_load_lds((const __attribute__((address_space(1))) uint32_t*)g,
                                   (__attribute__((address_space(3))) uint32_t*)l, 16, 0, 0);
}

// ---- elementwise split: x -> f16(1024x) hi + f16 residual lo ----
__global__ __launch_bounds__(256) void split_kernel(
    const float* __restrict__ X, _Float16* __restrict__ hi, _Float16* __restrict__ lo)
{
  const int i = (blockIdx.x * 256 + threadIdx.x) * 4;
  float4 x = *(const float4*)(X + i);
  float xs[4] = {x.x, x.y, x.z, x.w};
  union { half4v v; _Float16 e[4]; } uh, ul;
#pragma unroll
  for (int j = 0; j < 4; ++j) {
    float s = xs[j] * 1024.0f;          // exact pow2 scale
    _Float16 h = (_Float16)s;           // RN
    uh.e[j] = h;
    ul.e[j] = (_Float16)(s - (float)h); // RN of exact residual
  }
  *(half4v*)(hi + i) = uh.v;
  *(half4v*)(lo + i) = ul.v;
}

// ---- row sum-of-squares, numpy pairwise order, coalesced via LDS transpose ----
// one wave per block, 64 rows per block, k-tiles of 64 cols
__global__ __launch_bounds__(64) void rowsq_kernel(
    const float* __restrict__ x, float* __restrict__ out)
{
  __shared__ float T[64 * 68];
  const int l = threadIdx.x;
  const int r0 = blockIdx.x * 64;
  float rj[8];
  float s0 = 0.0f, s1 = 0.0f;
#pragma unroll
  for (int kt = 0; kt < 4; ++kt) {
    __syncthreads();
#pragma unroll
    for (int s = 0; s < 16; ++s) {      // stage 64 rows x 64 cols, coalesced f4
      const int row = s * 4 + (l >> 4), c4 = l & 15;
      float4 v = *(const float4*)(x + (size_t)(r0 + row) * D_DIM + kt * 64 + c4 * 4);
      *(float4*)&T[row * 68 + c4 * 4] = v;
    }
    __syncthreads();
#pragma unroll
    for (int c4 = 0; c4 < 16; ++c4) {   // thread l consumes row l, np chain order
      float4 v = *(const float4*)&T[l * 68 + c4 * 4];
      float e[4] = {v.x, v.y, v.z, v.w};
#pragma unroll
      for (int t = 0; t < 4; ++t) {
        const int k = kt * 64 + c4 * 4 + t;
        const int j = k & 7;
        float sq = __fmul_rn(e[t], e[t]);
        if ((k & 127) < 8) rj[j] = sq;
        else rj[j] = __fadd_rn(rj[j], sq);
      }
    }
    if (kt == 1) s0 = __fadd_rn(__fadd_rn(__fadd_rn(rj[0], rj[1]), __fadd_rn(rj[2], rj[3])),
                                __fadd_rn(__fadd_rn(rj[4], rj[5]), __fadd_rn(rj[6], rj[7])));
    if (kt == 3) s1 = __fadd_rn(__fadd_rn(__fadd_rn(rj[0], rj[1]), __fadd_rn(rj[2], rj[3])),
                                __fadd_rn(__fadd_rn(rj[4], rj[5]), __fadd_rn(rj[6], rj[7])));
  }
  out[r0 + l] = __fadd_rn(s0, s1);
}

// ---- main: MFMA f16x3 GEMM + argmin; DMA-staged double-buffered A, B from L2 ----
// block 128m x 256n, 4 waves 2x2, wave tile 64m x 128n
__global__ __launch_bounds__(256, 2) void vq_mfma_kernel(
    const _Float16* __restrict__ Vhi, const _Float16* __restrict__ Vlo,
    const _Float16* __restrict__ Whi,
    const float* __restrict__ v2, const float* __restrict__ c2,
    uint64_t* __restrict__ pk)
{
  // 64 KB: [buf(2)][plane(2)][8192 halves]; image: m*64 + c*8 + j, c = kb ^ (m&7)
  __shared__ __align__(16) _Float16 lds[32768];

  const int tid  = threadIdx.x;
  const int lane = tid & 63;
  const int wave = tid >> 6;
  const int wr = wave >> 1, wc = wave & 1;
  const int row16 = lane & 15, quad = lane >> 4;
  const int m0 = blockIdx.x * 128;
  const int n0 = blockIdx.y * 256;

  // staging source map: q = tid + 256u -> m = q>>3, kb = (q&7) ^ (m&7)
  int soff[4];
#pragma unroll
  for (int u = 0; u < 4; ++u) {
    const int q = tid + 256 * u, m = q >> 3, kb = (q & 7) ^ (m & 7);
    soff[u] = (m0 + m) * D_DIM + kb * 8;   // halves; + kt*64 per tile
  }

  float4v acc[4][8];
#pragma unroll
  for (int mp = 0; mp < 4; ++mp)
#pragma unroll
    for (int np = 0; np < 8; ++np) acc[mp][np] = (float4v)0.0f;

  // prologue: DMA tile 0 into buf 0
#pragma unroll
  for (int u = 0; u < 4; ++u) {
    _Float16* dst = lds + wave * 512 + u * 2048;
    dma16(Vhi + soff[u], dst);
    dma16(Vlo + soff[u], dst + 8192);
  }

  for (int kt = 0; kt < 4; ++kt) {
    __syncthreads();                     // drains DMA, releases other buffer
    if (kt < 3) {                        // prefetch next tile into other buffer
      const int koff = (kt + 1) * 64;
      _Float16* base = lds + ((kt + 1) & 1) * 16384;
#pragma unroll
      for (int u = 0; u < 4; ++u) {
        _Float16* dst = base + wave * 512 + u * 2048;
        dma16(Vhi + soff[u] + koff, dst);
        dma16(Vlo + soff[u] + koff, dst + 8192);
      }
    }
    const _Float16* Ah = lds + (kt & 1) * 16384;
    const _Float16* Al = Ah + 8192;
#pragma unroll
    for (int ks = 0; ks < 2; ++ks) {
      half8 a_hi[4], a_lo[4];
#pragma unroll
      for (int mp = 0; mp < 4; ++mp) {
        const int m = wr * 64 + mp * 16 + row16;
        const int c = (ks * 4 + quad) ^ (m & 7);
        a_hi[mp] = *(const half8*)(Ah + m * 64 + c * 8);
        a_lo[mp] = *(const half8*)(Al + m * 64 + c * 8);
      }
#pragma unroll
      for (int np = 0; np < 8; ++np) {
        const _Float16* bp = Whi + (size_t)(n0 + wc * 128 + np * 16 + row16) * D_DIM
                             + kt * 64 + ks * 32 + quad * 8;
        half8 b_hi = *(const half8*)bp;
        half8 b_lo = *(const half8*)(bp + WPLANE);
#pragma unroll
        for (int mp = 0; mp < 4; ++mp) {
          acc[mp][np] = __builtin_amdgcn_mfma_f32_16x16x32_f16(a_hi[mp], b_hi, acc[mp][np], 0, 0, 0);
          acc[mp][np] = __builtin_amdgcn_mfma_f32_16x16x32_f16(a_hi[mp], b_lo, acc[mp][np], 0, 0, 0);
          acc[mp][np] = __builtin_amdgcn_mfma_f32_16x16x32_f16(a_lo[mp], b_hi, acc[mp][np], 0, 0, 0);
        }
      }
    }
  }

  // ---- epilogue: diff = (v2 - 2*dot) + c2 (np rounding order), argmin ----
  float v2r[4][4];
#pragma unroll
  for (int mp = 0; mp < 4; ++mp)
#pragma unroll
    for (int r = 0; r < 4; ++r)
      v2r[mp][r] = v2[m0 + wr * 64 + mp * 16 + quad * 4 + r];

  uint64_t best[4][4];
#pragma unroll
  for (int mp = 0; mp < 4; ++mp)
#pragma unroll
    for (int r = 0; r < 4; ++r) best[mp][r] = ~0ULL;

#pragma unroll
  for (int np = 0; np < 8; ++np) {
    const int n = n0 + wc * 128 + np * 16 + row16;
    const float c2n = c2[n];
#pragma unroll
    for (int mp = 0; mp < 4; ++mp)
#pragma unroll
      for (int r = 0; r < 4; ++r) {
        float dot = acc[mp][np][r] * 0x1p-20f;              // exact pow2 unscale
        float t   = __fsub_rn(v2r[mp][r], 2.0f * dot);
        float dd  = __fadd_rn(t, c2n);
        if (n == 0) dd = INFINITY;                          // exclude code 0
        uint64_t p = ((uint64_t)__float_as_uint(dd) << 32) | (uint32_t)n;
        if (p < best[mp][r]) best[mp][r] = p;               // dd>0 -> bits monotonic
      }
  }

  __syncthreads();   // done reading A-LDS; reuse as reduction buffer (stride 33)
  uint64_t* red = (uint64_t*)lds;
#pragma unroll
  for (int mp = 0; mp < 4; ++mp)
#pragma unroll
    for (int r = 0; r < 4; ++r)
      red[(wr * 64 + mp * 16 + quad * 4 + r) * 33 + wc * 16 + row16] = best[mp][r];
  __syncthreads();
  if (tid < 128) {
    uint64_t b = red[tid * 33];
#pragma unroll
    for (int t = 1; t < 32; ++t) { uint64_t v = red[tid * 33 + t]; if (v < b) b = v; }
    pk[blockIdx.y * M_TOTAL + m0 + tid] = b;
  }
}

// ---- gather: one wave per query, no barriers ----
__global__ __launch_bounds__(256) void gather_kernel(
    const float* __restrict__ V, const float* __restrict__ W,
    const uint64_t* __restrict__ pk,
    float* __restrict__ out, float* __restrict__ outIdx,
    float* __restrict__ lossPartial)
{
  const int q = blockIdx.x * 4 + (threadIdx.x >> 6);
  const int l = threadIdx.x & 63;
  uint64_t b = (l < NPART) ? pk[(size_t)l * M_TOTAL + q] : ~0ULL;
#pragma unroll
  for (int off = 32; off; off >>= 1) {
    uint64_t o = __shfl_xor(b, off);
    if (o < b) b = o;
  }
  float4 vv = *(const float4*)(V + (size_t)q * D_DIM + l * 4);
  const float inv = 0.00390625f;
  bool ne = (vv.x != inv) | (vv.y != inv) | (vv.z != inv) | (vv.w != inv);
  const int idx = __ballot(ne) ? (int)(uint32_t)b : 0;
  float4 o4 = *(const float4*)(W + (size_t)idx * D_DIM + l * 4);
  *(float4*)(out + (size_t)q * D_DIM + l * 4) = o4;
  if (l == 0) outIdx[q] = (float)idx;
  float dx = o4.x - vv.x, dy = o4.y - vv.y, dz = o4.z - vv.z, dw = o4.w - vv.w;
  float s = dx * dx + dy * dy + dz * dz + dw * dw;
#pragma unroll
  for (int off = 32; off; off >>= 1) s += __shfl_xor(s, off);
  if (l == 0) lossPartial[q] = s;
}

__global__ __launch_bounds__(256) void finalize_kernel(
    const float* __restrict__ lossPartial, float* __restrict__ out)
{
  const int t = threadIdx.x;
  __shared__ float red[256];
  float s = 0.0f;
  for (int i = t; i < M_TOTAL; i += 256) s += lossPartial[i];
  red[t] = s;
  __syncthreads();
  for (int st = 128; st > 0; st >>= 1) {
    if (t < st) red[t] += red[t + st];
    __syncthreads();
  }
  if (t == 0) {
    out[0] = (float)((double)red[0] / (double)(M_TOTAL * D_DIM));  // loss
    out[1] = 0.0f;                                                 // used
  }
}

extern "C" void kernel_launch(void* const* d_in, const int* in_sizes, int n_in,
                              void* d_out, int out_size, void* d_ws, size_t ws_size,
                              hipStream_t stream) {
  const float* V = (const float*)d_in[0];   // 16384 x 256
  const float* W = (const float*)d_in[1];   // 4096 x 256
  float* out = (float*)d_out;

  // V planes live in d_out (exactly 16384*256*4 bytes); gather overwrites later.
  _Float16* Vhi = (_Float16*)d_out;
  _Float16* Vlo = Vhi + VPLANE;

  char* ws = (char*)d_ws;
  _Float16* Whi = (_Float16*)(ws);                        // 2 MB
  _Float16* Wlo = (_Float16*)(ws + 2097152);              // 2 MB (= Whi + WPLANE)
  float*    c2  = (float*)(ws + 4194304);                 // 16 KB
  float*    v2  = (float*)(ws + 4194304 + 16384);         // 64 KB
  uint64_t* pk  = (uint64_t*)(ws + 4194304 + 16384 + 65536);   // 16*16384*8 = 2 MB
  float* lossPartial = (float*)(ws + 4194304 + 16384 + 65536 + 2097152);

  split_kernel<<<WPLANE / 1024, 256, 0, stream>>>(W, Whi, Wlo);
  split_kernel<<<VPLANE / 1024, 256, 0, stream>>>(V, Vhi, Vlo);
  rowsq_kernel<<<NCODES / 64, 64, 0, stream>>>(W, c2);
  rowsq_kernel<<<M_TOTAL / 64, 64, 0, stream>>>(V, v2);
  vq_mfma_kernel<<<dim3(M_TOTAL / 128, NCODES / 256), 256, 0, stream>>>(Vhi, Vlo, Whi, v2, c2, pk);
  gather_kernel<<<M_TOTAL / 4, 256, 0, stream>>>(V, W, pk, out, out + OUT_OFF_IDX, lossPartial);
  finalize_kernel<<<1, 256, 0, stream>>>(lossPartial, out + OUT_OFF_LOSS);
}